// Round 1
// baseline (2461.676 us; speedup 1.0000x reference)
//
#include <hip/hip_runtime.h>
#include <math.h>

#define TAUF 0.9f

__device__ __forceinline__ float wave_sum(float v) {
#pragma unroll
  for (int off = 32; off > 0; off >>= 1) v += __shfl_down(v, off, 64);
  return __shfl(v, 0, 64);
}

// ---------------- GEMM: C = epi(A@B + bias) [+ R] ----------------
// EPI: 0 bias, 1 relu, 2 gelu(exact), 3 bias + residual R
// Requires N % 64 == 0. Tiles: BM=64, BN=64, BK=16; block=256, 4x4 microtile.
template <int EPI>
__launch_bounds__(256)
__global__ void gemm64(const float* __restrict__ A, const float* __restrict__ B,
                       const float* __restrict__ bias, const float* __restrict__ R,
                       float* __restrict__ C, int M, int N, int K) {
  __shared__ float As[16][64];  // [k][m]
  __shared__ float Bs[16][64];  // [k][n]
  const int tid = threadIdx.x;
  const int tx = tid & 15, ty = tid >> 4;
  const int bm = blockIdx.x * 64, bn = blockIdx.y * 64;
  const int aRow = (tid * 4) >> 4, aCol = (tid * 4) & 15;
  const int bRow = (tid * 4) >> 6, bCol = (tid * 4) & 63;
  float acc[4][4] = {};
  for (int k0 = 0; k0 < K; k0 += 16) {
    float4 av = make_float4(0.f, 0.f, 0.f, 0.f);
    if (bm + aRow < M)
      av = *reinterpret_cast<const float4*>(A + (size_t)(bm + aRow) * K + k0 + aCol);
    As[aCol + 0][aRow] = av.x;
    As[aCol + 1][aRow] = av.y;
    As[aCol + 2][aRow] = av.z;
    As[aCol + 3][aRow] = av.w;
    *reinterpret_cast<float4*>(&Bs[bRow][bCol]) =
        *reinterpret_cast<const float4*>(B + (size_t)(k0 + bRow) * N + bn + bCol);
    __syncthreads();
#pragma unroll
    for (int k = 0; k < 16; ++k) {
      float4 a4 = *reinterpret_cast<const float4*>(&As[k][ty * 4]);
      float4 b4 = *reinterpret_cast<const float4*>(&Bs[k][tx * 4]);
      float ar[4] = {a4.x, a4.y, a4.z, a4.w};
      float br[4] = {b4.x, b4.y, b4.z, b4.w};
#pragma unroll
      for (int i = 0; i < 4; ++i)
#pragma unroll
        for (int j = 0; j < 4; ++j) acc[i][j] += ar[i] * br[j];
    }
    __syncthreads();
  }
  float4 bb4 = *reinterpret_cast<const float4*>(bias + bn + tx * 4);
  float bb[4] = {bb4.x, bb4.y, bb4.z, bb4.w};
#pragma unroll
  for (int i = 0; i < 4; ++i) {
    int r = bm + ty * 4 + i;
    if (r >= M) continue;
    float v[4];
#pragma unroll
    for (int j = 0; j < 4; ++j) v[j] = acc[i][j] + bb[j];
    if (EPI == 1) {
#pragma unroll
      for (int j = 0; j < 4; ++j) v[j] = fmaxf(v[j], 0.f);
    } else if (EPI == 2) {
#pragma unroll
      for (int j = 0; j < 4; ++j)
        v[j] = v[j] * 0.5f * (1.f + erff(v[j] * 0.70710678118654752f));
    } else if (EPI == 3) {
      float4 r4 = *reinterpret_cast<const float4*>(R + (size_t)r * N + bn + tx * 4);
      v[0] += r4.x; v[1] += r4.y; v[2] += r4.z; v[3] += r4.w;
    }
    *reinterpret_cast<float4*>(C + (size_t)r * N + bn + tx * 4) =
        make_float4(v[0], v[1], v[2], v[3]);
  }
}

__global__ void zero_k(float* __restrict__ p, int n) {
  int i = blockIdx.x * 256 + threadIdx.x;
  if (i < n) p[i] = 0.f;
}

// per-row: delta=sum|x|, adst=x.Wa[0:256], asrc=x.Wa[256:512], xwp=x.wp
__global__ void rowstats_k(const float* __restrict__ h, const float* __restrict__ Wa,
                           const float* __restrict__ wp, float* __restrict__ delta,
                           float* __restrict__ adst, float* __restrict__ asrc,
                           float* __restrict__ xwp, int N) {
  int row = blockIdx.x * 4 + (threadIdx.x >> 6);
  if (row >= N) return;
  int lane = threadIdx.x & 63;
  const float* x = h + (size_t)row * 256;
  float sd = 0.f, s1 = 0.f, s2 = 0.f, s3 = 0.f;
#pragma unroll
  for (int q = 0; q < 4; ++q) {
    int c = lane + 64 * q;
    float v = x[c];
    sd += fabsf(v);
    s1 += v * Wa[c];
    s2 += v * Wa[256 + c];
    s3 += v * wp[c];
  }
  sd = wave_sum(sd); s1 = wave_sum(s1); s2 = wave_sum(s2); s3 = wave_sum(s3);
  if (lane == 0) { delta[row] = sd; adst[row] = s1; asrc[row] = s2; xwp[row] = s3; }
}

__global__ void neigh_k(const int* __restrict__ src, const int* __restrict__ dst,
                        const float* __restrict__ delta, float* __restrict__ neigh, int E) {
  int e = blockIdx.x * 256 + threadIdx.x;
  if (e < E) atomicAdd(&neigh[dst[e]], delta[src[e]]);
}

__global__ void pi_k(const float* __restrict__ xwp, const float* __restrict__ neigh,
                     float* __restrict__ pi, int N) {
  int i = blockIdx.x * 256 + threadIdx.x;
  if (i < N) pi[i] = 1.f / (1.f + expf(-(xwp[i] + neigh[i])));
}

// edge logits -> exp; accumulate denom; bucket edge ids per destination
__global__ void logits_k(const int* __restrict__ src, const int* __restrict__ dst,
                         const float* __restrict__ adst, const float* __restrict__ asrc,
                         const float* __restrict__ pi, const float* __restrict__ Wa,
                         const float* __restrict__ ba, float* __restrict__ expe,
                         float* __restrict__ denom, int* __restrict__ cnt,
                         int* __restrict__ slots, int E, int Et) {
  int e = blockIdx.x * 256 + threadIdx.x;
  if (e >= Et) return;
  int s, d;
  if (e < E) { s = src[e]; d = dst[e]; } else { s = e - E; d = s; }
  float v = adst[d] + asrc[s] + pi[s] * Wa[512] + ba[0];
  v = (v >= 0.f ? v : 0.2f * v) / TAUF;
  v = fminf(fmaxf(v, -5.f), 5.f);
  float ex = expf(v);
  expe[e] = ex;
  atomicAdd(&denom[d], ex);
  int p = atomicAdd(&cnt[d], 1);
  if (p < 64) slots[(size_t)d * 64 + p] = e;
}

__device__ __forceinline__ bool better(float a, int e, float a2, int e2) {
  return a > a2 || (a == a2 && e < e2);  // alpha desc, tie: lower original index
}

// per-destination top-8 + renormalize; emit compact (src, weight) lists
__global__ void topk_k(const int* __restrict__ cnt, const int* __restrict__ slots,
                       const float* __restrict__ expe, const float* __restrict__ denom,
                       const int* __restrict__ src, int* __restrict__ kcnt,
                       int* __restrict__ ksrc, float* __restrict__ kw, int N, int E) {
  int d = blockIdx.x * 256 + threadIdx.x;
  if (d >= N) return;
  int deg = min(cnt[d], 64);
  float D = denom[d] + 1e-16f;
  float av[8]; int ai[8]; int kc = 0;
  for (int t = 0; t < deg; ++t) {
    int e = slots[(size_t)d * 64 + t];
    float a = expe[e] / D;
    if (kc < 8) {
      int p = kc++;
      while (p > 0 && better(a, e, av[p - 1], ai[p - 1])) {
        av[p] = av[p - 1]; ai[p] = ai[p - 1]; --p;
      }
      av[p] = a; ai[p] = e;
    } else if (better(a, e, av[7], ai[7])) {
      int p = 7;
      while (p > 0 && better(a, e, av[p - 1], ai[p - 1])) {
        av[p] = av[p - 1]; ai[p] = ai[p - 1]; --p;
      }
      av[p] = a; ai[p] = e;
    }
  }
  float ks = 0.f;
  for (int j = 0; j < kc; ++j) ks += av[j];
  kcnt[d] = kc;
  for (int j = 0; j < kc; ++j) {
    int e = ai[j];
    ksrc[(size_t)d * 8 + j] = (e < E) ? src[e] : (e - E);
    kw[(size_t)d * 8 + j] = av[j] / (ks + 1e-16f);
  }
}

__global__ void ln_k(const float* __restrict__ h, const float* __restrict__ g,
                     const float* __restrict__ b, float* __restrict__ o, int N) {
  int row = blockIdx.x * 4 + (threadIdx.x >> 6);
  if (row >= N) return;
  int lane = threadIdx.x & 63;
  const float* x = h + (size_t)row * 256;
  float v[4];
#pragma unroll
  for (int q = 0; q < 4; ++q) v[q] = x[lane + 64 * q];
  float s = wave_sum(v[0] + v[1] + v[2] + v[3]);
  float mu = s * (1.f / 256.f);
  float qv = 0.f;
#pragma unroll
  for (int q = 0; q < 4; ++q) { float t = v[q] - mu; qv += t * t; }
  qv = wave_sum(qv);
  float is = rsqrtf(qv * (1.f / 256.f) + 1e-5f);
  float* orow = o + (size_t)row * 256;
#pragma unroll
  for (int q = 0; q < 4; ++q) {
    int c = lane + 64 * q;
    orow[c] = (v[q] - mu) * is * g[c] + b[c];
  }
}

// h[d] += relu( sum_j kw[d,j] * xp[ksrc[d,j]] )  (one wave per destination)
__global__ void agg_k(const float* __restrict__ xp, const int* __restrict__ kcnt,
                      const int* __restrict__ ksrc, const float* __restrict__ kw,
                      float* __restrict__ h, int N) {
  int d = blockIdx.x * 4 + (threadIdx.x >> 6);
  if (d >= N) return;
  int lane = threadIdx.x & 63;
  int kc = kcnt[d];
  float acc[4] = {0.f, 0.f, 0.f, 0.f};
  for (int j = 0; j < kc; ++j) {
    int s = ksrc[(size_t)d * 8 + j];
    float w = kw[(size_t)d * 8 + j];
    const float* xr = xp + (size_t)s * 256;
#pragma unroll
    for (int q = 0; q < 4; ++q) acc[q] += w * xr[lane + 64 * q];
  }
  float* hr = h + (size_t)d * 256;
#pragma unroll
  for (int q = 0; q < 4; ++q) hr[lane + 64 * q] += fmaxf(acc[q], 0.f);
}

extern "C" void kernel_launch(void* const* d_in, const int* in_sizes, int n_in,
                              void* d_out, int out_size, void* d_ws, size_t ws_size,
                              hipStream_t stream) {
  const float* X   = (const float*)d_in[0];
  const int*   EI  = (const int*)d_in[1];
  const float* Wi  = (const float*)d_in[2];
  const float* bi  = (const float*)d_in[3];
  const float* wp  = (const float*)d_in[4];
  const float* Wa  = (const float*)d_in[5];
  const float* ba  = (const float*)d_in[6];
  const float* l1g = (const float*)d_in[7];
  const float* l1b = (const float*)d_in[8];
  const float* l2g = (const float*)d_in[9];
  const float* l2b = (const float*)d_in[10];
  const float* W1  = (const float*)d_in[11];
  const float* b1  = (const float*)d_in[12];
  const float* W2  = (const float*)d_in[13];
  const float* b2  = (const float*)d_in[14];
  const float* Wc  = (const float*)d_in[15];
  const float* bc  = (const float*)d_in[16];
  const float* Wo  = (const float*)d_in[17];
  const float* bo  = (const float*)d_in[18];

  const int N = in_sizes[0] / 256;
  const int E = in_sizes[1] / 2;
  const int Et = E + N;
  const int* srcp = EI;
  const int* dstp = EI + E;

  float* ws = (float*)d_ws;
  size_t off = 0;
  auto alloc = [&](size_t n) { float* p = ws + off; off += n; return p; };
  const size_t NH = (size_t)N * 256;
  float* h  = alloc(NH);
  float* hn = alloc(NH);
  float* xp = alloc(NH);
  const int RCH = (N + 3) / 4;  // FFN row chunk
  float* u  = alloc((size_t)RCH * 512);
  float* delta = alloc(N);
  float* adst  = alloc(N);
  float* asrc  = alloc(N);
  float* xwp   = alloc(N);
  float* pib   = alloc(N);
  float* expe  = alloc(Et);
  float* neigh = alloc(N);      // ┐ contiguous zero region (3N)
  float* denom = alloc(N);      // │
  int*   cnt   = (int*)alloc(N);// ┘
  int*   slots = (int*)alloc((size_t)N * 64);
  int*   kcnt  = (int*)alloc(N);
  int*   ksrc  = (int*)alloc((size_t)N * 8);
  float* kw    = alloc((size_t)N * 8);

  // zero atomic accumulators (must happen every call)
  zero_k<<<(3 * N + 255) / 256, 256, 0, stream>>>(neigh, 3 * N);

  // input projection + relu
  gemm64<1><<<dim3((N + 63) / 64, 4), 256, 0, stream>>>(X, Wi, bi, nullptr, h, N, 256, 256);
  // row reductions
  rowstats_k<<<(N + 3) / 4, 256, 0, stream>>>(h, Wa, wp, delta, adst, asrc, xwp, N);
  // neighbor priority sum (real edges only)
  neigh_k<<<(E + 255) / 256, 256, 0, stream>>>(srcp, dstp, delta, neigh, E);
  pi_k<<<(N + 255) / 256, 256, 0, stream>>>(xwp, neigh, pib, N);
  // edge logits + denom + per-dst bucketing (edges + self loops)
  logits_k<<<(Et + 255) / 256, 256, 0, stream>>>(srcp, dstp, adst, asrc, pib, Wa, ba,
                                                 expe, denom, cnt, slots, E, Et);
  // per-dst top-8 + renormalize
  topk_k<<<(N + 255) / 256, 256, 0, stream>>>(cnt, slots, expe, denom, srcp,
                                              kcnt, ksrc, kw, N, E);

  for (int l = 0; l < 3; ++l) {
    ln_k<<<(N + 3) / 4, 256, 0, stream>>>(h, l1g + l * 256, l1b + l * 256, hn, N);
    gemm64<0><<<dim3((N + 63) / 64, 4), 256, 0, stream>>>(
        hn, Wc + (size_t)l * 65536, bc + l * 256, nullptr, xp, N, 256, 256);
    agg_k<<<(N + 3) / 4, 256, 0, stream>>>(xp, kcnt, ksrc, kw, h, N);
    ln_k<<<(N + 3) / 4, 256, 0, stream>>>(h, l2g + l * 256, l2b + l * 256, hn, N);
    for (int c = 0; c < 4; ++c) {
      int r0 = c * RCH;
      int Mc = (N - r0 < RCH) ? (N - r0) : RCH;
      if (Mc <= 0) break;
      gemm64<2><<<dim3((Mc + 63) / 64, 8), 256, 0, stream>>>(
          hn + (size_t)r0 * 256, W1 + (size_t)l * 131072, b1 + l * 512, nullptr,
          u, Mc, 512, 256);
      gemm64<3><<<dim3((Mc + 63) / 64, 4), 256, 0, stream>>>(
          u, W2 + (size_t)l * 131072, b2 + l * 256, h + (size_t)r0 * 256,
          h + (size_t)r0 * 256, Mc, 256, 512);
    }
  }
  // output projection
  gemm64<0><<<dim3((N + 63) / 64, 1), 256, 0, stream>>>(h, Wo, bo, nullptr,
                                                        (float*)d_out, N, 64, 256);
}

// Round 2
// 941.935 us; speedup vs baseline: 2.6134x; 2.6134x over previous
//
#include <hip/hip_runtime.h>
#include <math.h>

#define TAUF 0.9f

typedef unsigned int u32;
typedef unsigned short ushort;
typedef __attribute__((ext_vector_type(8))) short short8;
typedef __attribute__((ext_vector_type(4))) float f32x4;

__device__ __forceinline__ float wave_sum(float v) {
#pragma unroll
  for (int off = 32; off > 0; off >>= 1) v += __shfl_down(v, off, 64);
  return __shfl(v, 0, 64);
}

__device__ __forceinline__ ushort f2bf(float f) {
  u32 u = __builtin_bit_cast(u32, f);
  u32 r = (u + 0x7FFFu + ((u >> 16) & 1u)) >> 16;
  return (ushort)r;
}

__device__ __forceinline__ void gload16(const void* g, void* l) {
  __builtin_amdgcn_global_load_lds(
      (const __attribute__((address_space(1))) u32*)g,
      (__attribute__((address_space(3))) u32*)l, 16, 0, 0);
}

// ---------------- f32 GEMM (used only for input & output projection) ----------
// EPI: 0 bias, 1 bias+relu
template <int EPI>
__launch_bounds__(256)
__global__ void gemm64(const float* __restrict__ A, const float* __restrict__ B,
                       const float* __restrict__ bias, float* __restrict__ C,
                       int M, int N, int K) {
  __shared__ float As[16][64];
  __shared__ float Bs[16][64];
  const int tid = threadIdx.x;
  const int tx = tid & 15, ty = tid >> 4;
  const int bm = blockIdx.x * 64, bn = blockIdx.y * 64;
  const int aRow = (tid * 4) >> 4, aCol = (tid * 4) & 15;
  const int bRow = (tid * 4) >> 6, bCol = (tid * 4) & 63;
  float acc[4][4] = {};
  for (int k0 = 0; k0 < K; k0 += 16) {
    float4 av = make_float4(0.f, 0.f, 0.f, 0.f);
    if (bm + aRow < M)
      av = *reinterpret_cast<const float4*>(A + (size_t)(bm + aRow) * K + k0 + aCol);
    As[aCol + 0][aRow] = av.x;
    As[aCol + 1][aRow] = av.y;
    As[aCol + 2][aRow] = av.z;
    As[aCol + 3][aRow] = av.w;
    *reinterpret_cast<float4*>(&Bs[bRow][bCol]) =
        *reinterpret_cast<const float4*>(B + (size_t)(k0 + bRow) * N + bn + bCol);
    __syncthreads();
#pragma unroll
    for (int k = 0; k < 16; ++k) {
      float4 a4 = *reinterpret_cast<const float4*>(&As[k][ty * 4]);
      float4 b4 = *reinterpret_cast<const float4*>(&Bs[k][tx * 4]);
      float ar[4] = {a4.x, a4.y, a4.z, a4.w};
      float br[4] = {b4.x, b4.y, b4.z, b4.w};
#pragma unroll
      for (int i = 0; i < 4; ++i)
#pragma unroll
        for (int j = 0; j < 4; ++j) acc[i][j] += ar[i] * br[j];
    }
    __syncthreads();
  }
  float4 bb4 = *reinterpret_cast<const float4*>(bias + bn + tx * 4);
  float bb[4] = {bb4.x, bb4.y, bb4.z, bb4.w};
#pragma unroll
  for (int i = 0; i < 4; ++i) {
    int r = bm + ty * 4 + i;
    if (r >= M) continue;
    float v[4];
#pragma unroll
    for (int j = 0; j < 4; ++j) v[j] = acc[i][j] + bb[j];
    if (EPI == 1) {
#pragma unroll
      for (int j = 0; j < 4; ++j) v[j] = fmaxf(v[j], 0.f);
    }
    *reinterpret_cast<float4*>(C + (size_t)r * N + bn + tx * 4) =
        make_float4(v[0], v[1], v[2], v[3]);
  }
}

// ---------------- bf16 MFMA GEMM: C = epi(A @ Bt^T + bias) -------------------
// A: [M][K] bf16, Bt: [N][K] bf16 (pre-transposed weights). BM=BN=128, BK=64.
// 256 threads = 4 waves, each wave owns a 64x64 quadrant (4x4 of 16x16 frags).
// Staging: global_load_lds w16, linear LDS dest, inverse-XOR-swizzled global
// source; reads apply the same swizzle (rule #21).  EPI: 0 bias->f32,
// 2 bias+gelu->bf16, 3 bias + residual RMW on f32 C.
template <int EPI>
__launch_bounds__(256)
__global__ void gemm_mfma(const ushort* __restrict__ A, const ushort* __restrict__ Bt,
                          const float* __restrict__ bias, float* __restrict__ Cf,
                          ushort* __restrict__ Cb, int M, int N, int K) {
  __shared__ ushort As[128 * 64];
  __shared__ ushort Bs[128 * 64];
  const int tid = threadIdx.x;
  const int wave = tid >> 6, lane = tid & 63;
  const int bm = blockIdx.x * 128, bn = blockIdx.y * 128;
  const int wm = (wave >> 1) * 64, wn = (wave & 1) * 64;
  // staging constants: chunk c covers LDS bytes [c*1024, c*1024+1024)
  // lane covers bytes c*1024 + lane*16 -> row = c*8 + (lane>>3), physical col
  // byte = (lane&7)*16; logical col elem = ((lane&7) ^ (lane>>3)) * 8
  const int srow = lane >> 3;
  const int scol = (((lane & 7) ^ srow) << 3);

  f32x4 acc[4][4] = {{{0.f, 0.f, 0.f, 0.f}}};

  for (int k0 = 0; k0 < K; k0 += 64) {
#pragma unroll
    for (int r = 0; r < 4; ++r) {
      const int ch = r * 4 + wave;
      int ar = bm + ch * 8 + srow;
      ar = (ar < M) ? ar : (M - 1);
      gload16(A + (size_t)ar * K + k0 + scol, (char*)As + ch * 1024);
      const int br = bn + ch * 8 + srow;
      gload16(Bt + (size_t)br * K + k0 + scol, (char*)Bs + ch * 1024);
    }
    __syncthreads();
#pragma unroll
    for (int kk = 0; kk < 2; ++kk) {
      const int c = (kk * 32 + (lane >> 4) * 8) * 2;  // logical col byte
      short8 a[4], b[4];
#pragma unroll
      for (int mi = 0; mi < 4; ++mi) {
        const int rr = wm + mi * 16 + (lane & 15);
        a[mi] = *(const short8*)((const char*)As + rr * 128 + (c ^ ((rr & 7) << 4)));
      }
#pragma unroll
      for (int ni = 0; ni < 4; ++ni) {
        const int rr = wn + ni * 16 + (lane & 15);
        b[ni] = *(const short8*)((const char*)Bs + rr * 128 + (c ^ ((rr & 7) << 4)));
      }
#pragma unroll
      for (int mi = 0; mi < 4; ++mi)
#pragma unroll
        for (int ni = 0; ni < 4; ++ni)
          acc[mi][ni] = __builtin_amdgcn_mfma_f32_16x16x32_bf16(a[mi], b[ni],
                                                                acc[mi][ni], 0, 0, 0);
    }
    __syncthreads();
  }

  float bb[4];
#pragma unroll
  for (int ni = 0; ni < 4; ++ni) bb[ni] = bias[bn + wn + ni * 16 + (lane & 15)];
#pragma unroll
  for (int mi = 0; mi < 4; ++mi) {
#pragma unroll
    for (int reg = 0; reg < 4; ++reg) {
      const int row = bm + wm + mi * 16 + (lane >> 4) * 4 + reg;
      if (row >= M) continue;
#pragma unroll
      for (int ni = 0; ni < 4; ++ni) {
        const int col = bn + wn + ni * 16 + (lane & 15);
        float v = acc[mi][ni][reg] + bb[ni];
        if (EPI == 0) {
          Cf[(size_t)row * N + col] = v;
        } else if (EPI == 2) {
          v = v * 0.5f * (1.f + erff(v * 0.70710678118654752f));
          Cb[(size_t)row * N + col] = f2bf(v);
        } else {  // EPI == 3: residual RMW
          Cf[(size_t)row * N + col] += v;
        }
      }
    }
  }
}

// W [L][K][N] f32  ->  Wt [L][N][K] bf16
__global__ void wtrans_k(const float* __restrict__ W, ushort* __restrict__ Wt,
                         int K, int N, int total) {
  int i = blockIdx.x * 256 + threadIdx.x;
  if (i >= total) return;
  int KN = K * N;
  int l = i / KN, r2 = i - l * KN;
  int n = r2 / K, k = r2 - n * K;
  Wt[i] = f2bf(W[(size_t)l * KN + (size_t)k * N + n]);
}

__global__ void zero_k(float* __restrict__ p, int n) {
  int i = blockIdx.x * 256 + threadIdx.x;
  if (i < n) p[i] = 0.f;
}

__global__ void rowstats_k(const float* __restrict__ h, const float* __restrict__ Wa,
                           const float* __restrict__ wp, float* __restrict__ delta,
                           float* __restrict__ adst, float* __restrict__ asrc,
                           float* __restrict__ xwp, int N) {
  int row = blockIdx.x * 4 + (threadIdx.x >> 6);
  if (row >= N) return;
  int lane = threadIdx.x & 63;
  const float* x = h + (size_t)row * 256;
  float sd = 0.f, s1 = 0.f, s2 = 0.f, s3 = 0.f;
#pragma unroll
  for (int q = 0; q < 4; ++q) {
    int c = lane + 64 * q;
    float v = x[c];
    sd += fabsf(v);
    s1 += v * Wa[c];
    s2 += v * Wa[256 + c];
    s3 += v * wp[c];
  }
  sd = wave_sum(sd); s1 = wave_sum(s1); s2 = wave_sum(s2); s3 = wave_sum(s3);
  if (lane == 0) { delta[row] = sd; adst[row] = s1; asrc[row] = s2; xwp[row] = s3; }
}

__global__ void neigh_k(const int* __restrict__ src, const int* __restrict__ dst,
                        const float* __restrict__ delta, float* __restrict__ neigh, int E) {
  int e = blockIdx.x * 256 + threadIdx.x;
  if (e < E) atomicAdd(&neigh[dst[e]], delta[src[e]]);
}

__global__ void pi_k(const float* __restrict__ xwp, const float* __restrict__ neigh,
                     float* __restrict__ pi, int N) {
  int i = blockIdx.x * 256 + threadIdx.x;
  if (i < N) pi[i] = 1.f / (1.f + expf(-(xwp[i] + neigh[i])));
}

__global__ void logits_k(const int* __restrict__ src, const int* __restrict__ dst,
                         const float* __restrict__ adst, const float* __restrict__ asrc,
                         const float* __restrict__ pi, const float* __restrict__ Wa,
                         const float* __restrict__ ba, float* __restrict__ expe,
                         float* __restrict__ denom, int* __restrict__ cnt,
                         int* __restrict__ slots, int E, int Et) {
  int e = blockIdx.x * 256 + threadIdx.x;
  if (e >= Et) return;
  int s, d;
  if (e < E) { s = src[e]; d = dst[e]; } else { s = e - E; d = s; }
  float v = adst[d] + asrc[s] + pi[s] * Wa[512] + ba[0];
  v = (v >= 0.f ? v : 0.2f * v) / TAUF;
  v = fminf(fmaxf(v, -5.f), 5.f);
  float ex = expf(v);
  expe[e] = ex;
  atomicAdd(&denom[d], ex);
  int p = atomicAdd(&cnt[d], 1);
  if (p < 64) slots[(size_t)d * 64 + p] = e;
}

__device__ __forceinline__ bool better(float a, int e, float a2, int e2) {
  return a > a2 || (a == a2 && e < e2);
}

__global__ void topk_k(const int* __restrict__ cnt, const int* __restrict__ slots,
                       const float* __restrict__ expe, const float* __restrict__ denom,
                       const int* __restrict__ src, int* __restrict__ kcnt,
                       int* __restrict__ ksrc, float* __restrict__ kw, int N, int E) {
  int d = blockIdx.x * 256 + threadIdx.x;
  if (d >= N) return;
  int deg = min(cnt[d], 64);
  float D = denom[d] + 1e-16f;
  float av[8]; int ai[8]; int kc = 0;
  for (int t = 0; t < deg; ++t) {
    int e = slots[(size_t)d * 64 + t];
    float a = expe[e] / D;
    if (kc < 8) {
      int p = kc++;
      while (p > 0 && better(a, e, av[p - 1], ai[p - 1])) {
        av[p] = av[p - 1]; ai[p] = ai[p - 1]; --p;
      }
      av[p] = a; ai[p] = e;
    } else if (better(a, e, av[7], ai[7])) {
      int p = 7;
      while (p > 0 && better(a, e, av[p - 1], ai[p - 1])) {
        av[p] = av[p - 1]; ai[p] = ai[p - 1]; --p;
      }
      av[p] = a; ai[p] = e;
    }
  }
  float ks = 0.f;
  for (int j = 0; j < kc; ++j) ks += av[j];
  kcnt[d] = kc;
  for (int j = 0; j < kc; ++j) {
    int e = ai[j];
    ksrc[(size_t)d * 8 + j] = (e < E) ? src[e] : (e - E);
    kw[(size_t)d * 8 + j] = av[j] / (ks + 1e-16f);
  }
}

// LayerNorm; writes bf16 (feeds MFMA GEMMs)
__global__ void ln_k(const float* __restrict__ h, const float* __restrict__ g,
                     const float* __restrict__ b, ushort* __restrict__ o, int N) {
  int row = blockIdx.x * 4 + (threadIdx.x >> 6);
  if (row >= N) return;
  int lane = threadIdx.x & 63;
  const float* x = h + (size_t)row * 256;
  float v[4];
#pragma unroll
  for (int q = 0; q < 4; ++q) v[q] = x[lane + 64 * q];
  float s = wave_sum(v[0] + v[1] + v[2] + v[3]);
  float mu = s * (1.f / 256.f);
  float qv = 0.f;
#pragma unroll
  for (int q = 0; q < 4; ++q) { float t = v[q] - mu; qv += t * t; }
  qv = wave_sum(qv);
  float is = rsqrtf(qv * (1.f / 256.f) + 1e-5f);
  ushort* orow = o + (size_t)row * 256;
#pragma unroll
  for (int q = 0; q < 4; ++q) {
    int c = lane + 64 * q;
    orow[c] = f2bf((v[q] - mu) * is * g[c] + b[c]);
  }
}

__global__ void agg_k(const float* __restrict__ xp, const int* __restrict__ kcnt,
                      const int* __restrict__ ksrc, const float* __restrict__ kw,
                      float* __restrict__ h, int N) {
  int d = blockIdx.x * 4 + (threadIdx.x >> 6);
  if (d >= N) return;
  int lane = threadIdx.x & 63;
  int kc = kcnt[d];
  float acc[4] = {0.f, 0.f, 0.f, 0.f};
  for (int j = 0; j < kc; ++j) {
    int s = ksrc[(size_t)d * 8 + j];
    float w = kw[(size_t)d * 8 + j];
    const float* xr = xp + (size_t)s * 256;
#pragma unroll
    for (int q = 0; q < 4; ++q) acc[q] += w * xr[lane + 64 * q];
  }
  float* hr = h + (size_t)d * 256;
#pragma unroll
  for (int q = 0; q < 4; ++q) hr[lane + 64 * q] += fmaxf(acc[q], 0.f);
}

extern "C" void kernel_launch(void* const* d_in, const int* in_sizes, int n_in,
                              void* d_out, int out_size, void* d_ws, size_t ws_size,
                              hipStream_t stream) {
  const float* X   = (const float*)d_in[0];
  const int*   EI  = (const int*)d_in[1];
  const float* Wi  = (const float*)d_in[2];
  const float* bi  = (const float*)d_in[3];
  const float* wp  = (const float*)d_in[4];
  const float* Wa  = (const float*)d_in[5];
  const float* ba  = (const float*)d_in[6];
  const float* l1g = (const float*)d_in[7];
  const float* l1b = (const float*)d_in[8];
  const float* l2g = (const float*)d_in[9];
  const float* l2b = (const float*)d_in[10];
  const float* W1  = (const float*)d_in[11];
  const float* b1  = (const float*)d_in[12];
  const float* W2  = (const float*)d_in[13];
  const float* b2  = (const float*)d_in[14];
  const float* Wc  = (const float*)d_in[15];
  const float* bc  = (const float*)d_in[16];
  const float* Wo  = (const float*)d_in[17];
  const float* bo  = (const float*)d_in[18];

  const int N = in_sizes[0] / 256;
  const int E = in_sizes[1] / 2;
  const int Et = E + N;
  const int* srcp = EI;
  const int* dstp = EI + E;

  float* ws = (float*)d_ws;
  size_t off = 0;
  auto alloc = [&](size_t n) { float* p = ws + off; off += n; return p; };
  const size_t NH = (size_t)N * 256;
  float*  h    = alloc(NH);
  ushort* hn   = (ushort*)alloc(NH / 2);            // bf16 [N][256]
  float*  xp   = alloc(NH);
  ushort* u    = (ushort*)alloc((size_t)N * 512 / 2);  // bf16 [N][512]
  ushort* WcT  = (ushort*)alloc(3 * 65536 / 2);     // bf16 [3][256][256]
  ushort* W1T  = (ushort*)alloc(3 * 131072 / 2);    // bf16 [3][512][256]
  ushort* W2T  = (ushort*)alloc(3 * 131072 / 2);    // bf16 [3][256][512]
  float* delta = alloc(N);
  float* adst  = alloc(N);
  float* asrc  = alloc(N);
  float* xwp   = alloc(N);
  float* pib   = alloc(N);
  float* expe  = alloc(Et);
  float* neigh = alloc(N);       // ┐ contiguous zero region (3N)
  float* denom = alloc(N);       // │
  int*   cnt   = (int*)alloc(N); // ┘
  int*   slots = (int*)alloc((size_t)N * 64);
  int*   kcnt  = (int*)alloc(N);
  int*   ksrc  = (int*)alloc((size_t)N * 8);
  float* kw    = alloc((size_t)N * 8);

  // weight transpose+convert (per call; small)
  wtrans_k<<<(3 * 65536 + 255) / 256, 256, 0, stream>>>(Wc, WcT, 256, 256, 3 * 65536);
  wtrans_k<<<(3 * 131072 + 255) / 256, 256, 0, stream>>>(W1, W1T, 256, 512, 3 * 131072);
  wtrans_k<<<(3 * 131072 + 255) / 256, 256, 0, stream>>>(W2, W2T, 512, 256, 3 * 131072);

  // zero atomic accumulators
  zero_k<<<(3 * N + 255) / 256, 256, 0, stream>>>(neigh, 3 * N);

  // input projection + relu (f32: keeps top-k selection bit-exact vs reference)
  gemm64<1><<<dim3((N + 63) / 64, 4), 256, 0, stream>>>(X, Wi, bi, h, N, 256, 256);
  rowstats_k<<<(N + 3) / 4, 256, 0, stream>>>(h, Wa, wp, delta, adst, asrc, xwp, N);
  neigh_k<<<(E + 255) / 256, 256, 0, stream>>>(srcp, dstp, delta, neigh, E);
  pi_k<<<(N + 255) / 256, 256, 0, stream>>>(xwp, neigh, pib, N);
  logits_k<<<(Et + 255) / 256, 256, 0, stream>>>(srcp, dstp, adst, asrc, pib, Wa, ba,
                                                 expe, denom, cnt, slots, E, Et);
  topk_k<<<(N + 255) / 256, 256, 0, stream>>>(cnt, slots, expe, denom, srcp,
                                              kcnt, ksrc, kw, N, E);

  const int GM = (N + 127) / 128;
  for (int l = 0; l < 3; ++l) {
    ln_k<<<(N + 3) / 4, 256, 0, stream>>>(h, l1g + l * 256, l1b + l * 256, hn, N);
    gemm_mfma<0><<<dim3(GM, 2), 256, 0, stream>>>(
        hn, WcT + (size_t)l * 65536, bc + l * 256, xp, nullptr, N, 256, 256);
    agg_k<<<(N + 3) / 4, 256, 0, stream>>>(xp, kcnt, ksrc, kw, h, N);
    ln_k<<<(N + 3) / 4, 256, 0, stream>>>(h, l2g + l * 256, l2b + l * 256, hn, N);
    gemm_mfma<2><<<dim3(GM, 4), 256, 0, stream>>>(
        hn, W1T + (size_t)l * 131072, b1 + l * 512, nullptr, u, N, 512, 256);
    gemm_mfma<3><<<dim3(GM, 2), 256, 0, stream>>>(
        u, W2T + (size_t)l * 131072, b2 + l * 256, h, nullptr, N, 256, 512);
  }
  // output projection (f32)
  gemm64<0><<<dim3((N + 63) / 64, 1), 256, 0, stream>>>(h, Wo, bo, (float*)d_out,
                                                        N, 64, 256);
}

// Round 3
// 821.908 us; speedup vs baseline: 2.9951x; 1.1460x over previous
//
#include <hip/hip_runtime.h>
#include <math.h>

#define TAUF 0.9f

typedef unsigned int u32;
typedef unsigned short ushort;
typedef __attribute__((ext_vector_type(8))) short short8;
typedef __attribute__((ext_vector_type(4))) float f32x4;
typedef __attribute__((ext_vector_type(4))) unsigned short us4;

__device__ __forceinline__ float wave_sum(float v) {
#pragma unroll
  for (int off = 32; off > 0; off >>= 1) v += __shfl_down(v, off, 64);
  return __shfl(v, 0, 64);
}

__device__ __forceinline__ ushort f2bf(float f) {
  u32 u = __builtin_bit_cast(u32, f);
  u32 r = (u + 0x7FFFu + ((u >> 16) & 1u)) >> 16;
  return (ushort)r;
}
__device__ __forceinline__ float bf2f(ushort s) {
  u32 u = ((u32)s) << 16;
  return __builtin_bit_cast(float, u);
}

__device__ __forceinline__ void gload16(const void* g, void* l) {
  __builtin_amdgcn_global_load_lds(
      (const __attribute__((address_space(1))) u32*)g,
      (__attribute__((address_space(3))) u32*)l, 16, 0, 0);
}

// ---------------- f32 input GEMM: h = relu(X @ Wi + bi), fused row stats ----
// BM=64, BN=256 (full width), BK=16, 256 threads, 8x8 microtile.
// Epilogue also computes per-row delta/adst/asrc/xwp (half-wave reduce).
__launch_bounds__(256)
__global__ void gemm_in(const float* __restrict__ A, const float* __restrict__ B,
                        const float* __restrict__ bias, const float* __restrict__ Wa,
                        const float* __restrict__ wp, float* __restrict__ C,
                        float* __restrict__ delta, float* __restrict__ adst,
                        float* __restrict__ asrc, float* __restrict__ xwp,
                        int M, int K) {
  __shared__ float As[16][64];    // [k][m]
  __shared__ float Bs[16][256];   // [k][n]
  const int tid = threadIdx.x;
  const int tx = tid & 31, ty = tid >> 5;
  const int bm = blockIdx.x * 64;
  float acc[8][8] = {};
  const int aRow = tid >> 2, aC4 = (tid & 3) << 2;
  const int bR = tid >> 4, bC = (tid & 15) << 4;
  for (int k0 = 0; k0 < K; k0 += 16) {
    int ar = bm + aRow; ar = (ar < M) ? ar : (M - 1);
    float4 av = *reinterpret_cast<const float4*>(A + (size_t)ar * K + k0 + aC4);
    As[aC4 + 0][aRow] = av.x;
    As[aC4 + 1][aRow] = av.y;
    As[aC4 + 2][aRow] = av.z;
    As[aC4 + 3][aRow] = av.w;
#pragma unroll
    for (int t = 0; t < 4; ++t)
      *reinterpret_cast<float4*>(&Bs[bR][bC + t * 4]) =
          *reinterpret_cast<const float4*>(B + (size_t)(k0 + bR) * 256 + bC + t * 4);
    __syncthreads();
#pragma unroll
    for (int k = 0; k < 16; ++k) {
      float4 a0 = *reinterpret_cast<const float4*>(&As[k][ty * 8]);
      float4 a1 = *reinterpret_cast<const float4*>(&As[k][ty * 8 + 4]);
      float4 b0 = *reinterpret_cast<const float4*>(&Bs[k][tx * 8]);
      float4 b1 = *reinterpret_cast<const float4*>(&Bs[k][tx * 8 + 4]);
      float ar8[8] = {a0.x, a0.y, a0.z, a0.w, a1.x, a1.y, a1.z, a1.w};
      float br8[8] = {b0.x, b0.y, b0.z, b0.w, b1.x, b1.y, b1.z, b1.w};
#pragma unroll
      for (int i = 0; i < 8; ++i)
#pragma unroll
        for (int j = 0; j < 8; ++j) acc[i][j] += ar8[i] * br8[j];
    }
    __syncthreads();
  }
  // bias / Wa / wp slices for our 8 columns
  float bb[8], wa0[8], wa1[8], wpv[8];
#pragma unroll
  for (int t = 0; t < 2; ++t) {
    float4 b4 = *reinterpret_cast<const float4*>(bias + tx * 8 + t * 4);
    float4 w0 = *reinterpret_cast<const float4*>(Wa + tx * 8 + t * 4);
    float4 w1 = *reinterpret_cast<const float4*>(Wa + 256 + tx * 8 + t * 4);
    float4 wv = *reinterpret_cast<const float4*>(wp + tx * 8 + t * 4);
    bb[t * 4 + 0] = b4.x; bb[t * 4 + 1] = b4.y; bb[t * 4 + 2] = b4.z; bb[t * 4 + 3] = b4.w;
    wa0[t * 4 + 0] = w0.x; wa0[t * 4 + 1] = w0.y; wa0[t * 4 + 2] = w0.z; wa0[t * 4 + 3] = w0.w;
    wa1[t * 4 + 0] = w1.x; wa1[t * 4 + 1] = w1.y; wa1[t * 4 + 2] = w1.z; wa1[t * 4 + 3] = w1.w;
    wpv[t * 4 + 0] = wv.x; wpv[t * 4 + 1] = wv.y; wpv[t * 4 + 2] = wv.z; wpv[t * 4 + 3] = wv.w;
  }
#pragma unroll
  for (int i = 0; i < 8; ++i) {
    const int row = bm + ty * 8 + i;
    float v[8];
    float p0 = 0.f, p1 = 0.f, p2 = 0.f, p3 = 0.f;
#pragma unroll
    for (int j = 0; j < 8; ++j) {
      float t = acc[i][j] + bb[j];
      t = fmaxf(t, 0.f);
      v[j] = t;
      p0 += t;                // sum|x| (x>=0 post-relu)
      p1 += t * wa0[j];
      p2 += t * wa1[j];
      p3 += t * wpv[j];
    }
    if (row < M) {
      *reinterpret_cast<float4*>(C + (size_t)row * 256 + tx * 8) =
          make_float4(v[0], v[1], v[2], v[3]);
      *reinterpret_cast<float4*>(C + (size_t)row * 256 + tx * 8 + 4) =
          make_float4(v[4], v[5], v[6], v[7]);
    }
#pragma unroll
    for (int off = 16; off > 0; off >>= 1) {
      p0 += __shfl_xor(p0, off, 64);
      p1 += __shfl_xor(p1, off, 64);
      p2 += __shfl_xor(p2, off, 64);
      p3 += __shfl_xor(p3, off, 64);
    }
    if (tx == 0 && row < M) {
      delta[row] = p0; adst[row] = p1; asrc[row] = p2; xwp[row] = p3;
    }
  }
}

// ---------------- bf16 MFMA GEMM: C = epi(A @ Bt^T + bias) -------------------
// EPI: 1 bias->bf16, 2 bias+gelu->bf16, 3 bias+residual RMW on f32 Cf,
//      4 bias + Cf(read) -> bf16 Cb
template <int EPI>
__launch_bounds__(256)
__global__ void gemm_mfma(const ushort* __restrict__ A, const ushort* __restrict__ Bt,
                          const float* __restrict__ bias, float* __restrict__ Cf,
                          ushort* __restrict__ Cb, int M, int N, int K) {
  __shared__ ushort As[128 * 64];
  __shared__ ushort Bs[128 * 64];
  const int tid = threadIdx.x;
  const int wave = tid >> 6, lane = tid & 63;
  const int bm = blockIdx.x * 128, bn = blockIdx.y * 128;
  const int wm = (wave >> 1) * 64, wn = (wave & 1) * 64;
  const int srow = lane >> 3;
  const int scol = (((lane & 7) ^ srow) << 3);

  f32x4 acc[4][4];
#pragma unroll
  for (int i = 0; i < 4; ++i)
#pragma unroll
    for (int j = 0; j < 4; ++j) acc[i][j] = (f32x4){0.f, 0.f, 0.f, 0.f};

  for (int k0 = 0; k0 < K; k0 += 64) {
#pragma unroll
    for (int r = 0; r < 4; ++r) {
      const int ch = r * 4 + wave;
      int ar = bm + ch * 8 + srow;
      ar = (ar < M) ? ar : (M - 1);
      gload16(A + (size_t)ar * K + k0 + scol, (char*)As + ch * 1024);
      const int br = bn + ch * 8 + srow;
      gload16(Bt + (size_t)br * K + k0 + scol, (char*)Bs + ch * 1024);
    }
    __syncthreads();
#pragma unroll
    for (int kk = 0; kk < 2; ++kk) {
      const int c = (kk * 32 + (lane >> 4) * 8) * 2;
      short8 a[4], b[4];
#pragma unroll
      for (int mi = 0; mi < 4; ++mi) {
        const int rr = wm + mi * 16 + (lane & 15);
        a[mi] = *(const short8*)((const char*)As + rr * 128 + (c ^ ((rr & 7) << 4)));
      }
#pragma unroll
      for (int ni = 0; ni < 4; ++ni) {
        const int rr = wn + ni * 16 + (lane & 15);
        b[ni] = *(const short8*)((const char*)Bs + rr * 128 + (c ^ ((rr & 7) << 4)));
      }
#pragma unroll
      for (int mi = 0; mi < 4; ++mi)
#pragma unroll
        for (int ni = 0; ni < 4; ++ni)
          acc[mi][ni] = __builtin_amdgcn_mfma_f32_16x16x32_bf16(a[mi], b[ni],
                                                                acc[mi][ni], 0, 0, 0);
    }
    __syncthreads();
  }

  float bb[4];
#pragma unroll
  for (int ni = 0; ni < 4; ++ni) bb[ni] = bias[bn + wn + ni * 16 + (lane & 15)];
#pragma unroll
  for (int mi = 0; mi < 4; ++mi) {
#pragma unroll
    for (int reg = 0; reg < 4; ++reg) {
      const int row = bm + wm + mi * 16 + (lane >> 4) * 4 + reg;
      if (row >= M) continue;
#pragma unroll
      for (int ni = 0; ni < 4; ++ni) {
        const int col = bn + wn + ni * 16 + (lane & 15);
        float v = acc[mi][ni][reg] + bb[ni];
        if (EPI == 1) {
          Cb[(size_t)row * N + col] = f2bf(v);
        } else if (EPI == 2) {
          v = v * 0.5f * (1.f + erff(v * 0.70710678118654752f));
          Cb[(size_t)row * N + col] = f2bf(v);
        } else if (EPI == 3) {
          Cf[(size_t)row * N + col] += v;
        } else {  // EPI == 4
          v += Cf[(size_t)row * N + col];
          Cb[(size_t)row * N + col] = f2bf(v);
        }
      }
    }
  }
}

// ---------------- bf16 MFMA output GEMM: C(f32) = A @ Bt^T + bias ------------
// BM=128, BN=64 (=N), BK=64. 4 waves, each 32 rows x 64 cols.
__launch_bounds__(256)
__global__ void gemm_out(const ushort* __restrict__ A, const ushort* __restrict__ Bt,
                         const float* __restrict__ bias, float* __restrict__ C, int M) {
  __shared__ ushort As[128 * 64];
  __shared__ ushort Bs[64 * 64];
  const int tid = threadIdx.x;
  const int wave = tid >> 6, lane = tid & 63;
  const int bm = blockIdx.x * 128;
  const int wm = wave * 32;
  const int srow = lane >> 3;
  const int scol = (((lane & 7) ^ srow) << 3);
  f32x4 acc[2][4];
#pragma unroll
  for (int i = 0; i < 2; ++i)
#pragma unroll
    for (int j = 0; j < 4; ++j) acc[i][j] = (f32x4){0.f, 0.f, 0.f, 0.f};

  for (int k0 = 0; k0 < 256; k0 += 64) {
#pragma unroll
    for (int r = 0; r < 4; ++r) {
      const int ch = r * 4 + wave;
      int ar = bm + ch * 8 + srow;
      ar = (ar < M) ? ar : (M - 1);
      gload16(A + (size_t)ar * 256 + k0 + scol, (char*)As + ch * 1024);
    }
#pragma unroll
    for (int r = 0; r < 2; ++r) {
      const int ch = r * 4 + wave;
      const int br = ch * 8 + srow;
      gload16(Bt + (size_t)br * 256 + k0 + scol, (char*)Bs + ch * 1024);
    }
    __syncthreads();
#pragma unroll
    for (int kk = 0; kk < 2; ++kk) {
      const int c = (kk * 32 + (lane >> 4) * 8) * 2;
      short8 a[2], b[4];
#pragma unroll
      for (int mi = 0; mi < 2; ++mi) {
        const int rr = wm + mi * 16 + (lane & 15);
        a[mi] = *(const short8*)((const char*)As + rr * 128 + (c ^ ((rr & 7) << 4)));
      }
#pragma unroll
      for (int ni = 0; ni < 4; ++ni) {
        const int rr = ni * 16 + (lane & 15);
        b[ni] = *(const short8*)((const char*)Bs + rr * 128 + (c ^ ((rr & 7) << 4)));
      }
#pragma unroll
      for (int mi = 0; mi < 2; ++mi)
#pragma unroll
        for (int ni = 0; ni < 4; ++ni)
          acc[mi][ni] = __builtin_amdgcn_mfma_f32_16x16x32_bf16(a[mi], b[ni],
                                                                acc[mi][ni], 0, 0, 0);
    }
    __syncthreads();
  }
  float bb[4];
#pragma unroll
  for (int ni = 0; ni < 4; ++ni) bb[ni] = bias[ni * 16 + (lane & 15)];
#pragma unroll
  for (int mi = 0; mi < 2; ++mi) {
#pragma unroll
    for (int reg = 0; reg < 4; ++reg) {
      const int row = bm + wm + mi * 16 + (lane >> 4) * 4 + reg;
      if (row >= M) continue;
#pragma unroll
      for (int ni = 0; ni < 4; ++ni) {
        const int col = ni * 16 + (lane & 15);
        C[(size_t)row * 64 + col] = acc[mi][ni][reg] + bb[ni];
      }
    }
  }
}

// W [L][K][N] f32  ->  Wt [L][N][K] bf16
__global__ void wtrans_k(const float* __restrict__ W, ushort* __restrict__ Wt,
                         int K, int N, int total) {
  int i = blockIdx.x * 256 + threadIdx.x;
  if (i >= total) return;
  int KN = K * N;
  int l = i / KN, r2 = i - l * KN;
  int n = r2 / K, k = r2 - n * K;
  Wt[i] = f2bf(W[(size_t)l * KN + (size_t)k * N + n]);
}

__global__ void zero_k(float* __restrict__ p, int n) {
  int i = blockIdx.x * 256 + threadIdx.x;
  if (i < n) p[i] = 0.f;
}

__global__ void neigh_k(const int* __restrict__ src, const int* __restrict__ dst,
                        const float* __restrict__ delta, float* __restrict__ neigh, int E) {
  int e = blockIdx.x * 256 + threadIdx.x;
  if (e < E) atomicAdd(&neigh[dst[e]], delta[src[e]]);
}

__global__ void pi_k(const float* __restrict__ xwp, const float* __restrict__ neigh,
                     float* __restrict__ pi, int N) {
  int i = blockIdx.x * 256 + threadIdx.x;
  if (i < N) pi[i] = 1.f / (1.f + expf(-(xwp[i] + neigh[i])));
}

// slots layout: [t][N] (transposed for coalesced top-k scan)
__global__ void logits_k(const int* __restrict__ src, const int* __restrict__ dst,
                         const float* __restrict__ adst, const float* __restrict__ asrc,
                         const float* __restrict__ pi, const float* __restrict__ Wa,
                         const float* __restrict__ ba, float* __restrict__ expe,
                         float* __restrict__ denom, int* __restrict__ cnt,
                         int* __restrict__ slots, int E, int Et, int N) {
  int e = blockIdx.x * 256 + threadIdx.x;
  if (e >= Et) return;
  int s, d;
  if (e < E) { s = src[e]; d = dst[e]; } else { s = e - E; d = s; }
  float v = adst[d] + asrc[s] + pi[s] * Wa[512] + ba[0];
  v = (v >= 0.f ? v : 0.2f * v) / TAUF;
  v = fminf(fmaxf(v, -5.f), 5.f);
  float ex = expf(v);
  expe[e] = ex;
  atomicAdd(&denom[d], ex);
  int p = atomicAdd(&cnt[d], 1);
  if (p < 64) slots[(size_t)p * N + d] = e;
}

__device__ __forceinline__ bool better(float a, int e, float a2, int e2) {
  return a > a2 || (a == a2 && e < e2);
}

__global__ void topk_k(const int* __restrict__ cnt, const int* __restrict__ slots,
                       const float* __restrict__ expe, const float* __restrict__ denom,
                       const int* __restrict__ src, int* __restrict__ kcnt,
                       int* __restrict__ ksrc, float* __restrict__ kw, int N, int E) {
  int d = blockIdx.x * 256 + threadIdx.x;
  if (d >= N) return;
  int deg = min(cnt[d], 64);
  float D = denom[d] + 1e-16f;
  float av[8]; int ai[8]; int kc = 0;
  for (int t = 0; t < deg; ++t) {
    int e = slots[(size_t)t * N + d];
    float a = expe[e] / D;
    if (kc < 8) {
      int p = kc++;
      while (p > 0 && better(a, e, av[p - 1], ai[p - 1])) {
        av[p] = av[p - 1]; ai[p] = ai[p - 1]; --p;
      }
      av[p] = a; ai[p] = e;
    } else if (better(a, e, av[7], ai[7])) {
      int p = 7;
      while (p > 0 && better(a, e, av[p - 1], ai[p - 1])) {
        av[p] = av[p - 1]; ai[p] = ai[p - 1]; --p;
      }
      av[p] = a; ai[p] = e;
    }
  }
  float ks = 0.f;
  for (int j = 0; j < kc; ++j) ks += av[j];
  kcnt[d] = kc;
  for (int j = 0; j < kc; ++j) {
    int e = ai[j];
    ksrc[(size_t)d * 8 + j] = (e < E) ? src[e] : (e - E);
    kw[(size_t)d * 8 + j] = av[j] / (ks + 1e-16f);
  }
}

// LayerNorm (reads f32 h, writes bf16), float4 path, one wave per row
__global__ void ln_k(const float* __restrict__ h, const float* __restrict__ g,
                     const float* __restrict__ b, ushort* __restrict__ o, int N) {
  int row = blockIdx.x * 4 + (threadIdx.x >> 6);
  if (row >= N) return;
  int lane = threadIdx.x & 63;
  float4 v = *reinterpret_cast<const float4*>(h + (size_t)row * 256 + lane * 4);
  float s = wave_sum(v.x + v.y + v.z + v.w);
  float mu = s * (1.f / 256.f);
  float q = (v.x - mu) * (v.x - mu) + (v.y - mu) * (v.y - mu) +
            (v.z - mu) * (v.z - mu) + (v.w - mu) * (v.w - mu);
  q = wave_sum(q);
  float is = rsqrtf(q * (1.f / 256.f) + 1e-5f);
  float4 gg = *reinterpret_cast<const float4*>(g + lane * 4);
  float4 bb = *reinterpret_cast<const float4*>(b + lane * 4);
  us4 out;
  out.x = f2bf((v.x - mu) * is * gg.x + bb.x);
  out.y = f2bf((v.y - mu) * is * gg.y + bb.y);
  out.z = f2bf((v.z - mu) * is * gg.z + bb.z);
  out.w = f2bf((v.w - mu) * is * gg.w + bb.w);
  *reinterpret_cast<us4*>(o + (size_t)row * 256 + lane * 4) = out;
}

// fused: h += relu(sum_j kw*xp[ksrc]); then LN2 -> hn (bf16). One wave per row.
__global__ void agg_ln_k(const ushort* __restrict__ xp, const int* __restrict__ kcnt,
                         const int* __restrict__ ksrc, const float* __restrict__ kw,
                         const float* __restrict__ g, const float* __restrict__ b,
                         float* __restrict__ h, ushort* __restrict__ hn, int N) {
  int d = blockIdx.x * 4 + (threadIdx.x >> 6);
  if (d >= N) return;
  int lane = threadIdx.x & 63;
  int kc = kcnt[d];
  float a0 = 0.f, a1 = 0.f, a2 = 0.f, a3 = 0.f;
  for (int j = 0; j < kc; ++j) {
    int s = ksrc[(size_t)d * 8 + j];
    float w = kw[(size_t)d * 8 + j];
    us4 xv = *reinterpret_cast<const us4*>(xp + (size_t)s * 256 + lane * 4);
    a0 += w * bf2f(xv.x);
    a1 += w * bf2f(xv.y);
    a2 += w * bf2f(xv.z);
    a3 += w * bf2f(xv.w);
  }
  float* hr = h + (size_t)d * 256 + lane * 4;
  float4 hv = *reinterpret_cast<const float4*>(hr);
  float v0 = hv.x + fmaxf(a0, 0.f);
  float v1 = hv.y + fmaxf(a1, 0.f);
  float v2 = hv.z + fmaxf(a2, 0.f);
  float v3 = hv.w + fmaxf(a3, 0.f);
  *reinterpret_cast<float4*>(hr) = make_float4(v0, v1, v2, v3);
  float s = wave_sum(v0 + v1 + v2 + v3);
  float mu = s * (1.f / 256.f);
  float q = (v0 - mu) * (v0 - mu) + (v1 - mu) * (v1 - mu) +
            (v2 - mu) * (v2 - mu) + (v3 - mu) * (v3 - mu);
  q = wave_sum(q);
  float is = rsqrtf(q * (1.f / 256.f) + 1e-5f);
  float4 gg = *reinterpret_cast<const float4*>(g + lane * 4);
  float4 bb = *reinterpret_cast<const float4*>(b + lane * 4);
  us4 out;
  out.x = f2bf((v0 - mu) * is * gg.x + bb.x);
  out.y = f2bf((v1 - mu) * is * gg.y + bb.y);
  out.z = f2bf((v2 - mu) * is * gg.z + bb.z);
  out.w = f2bf((v3 - mu) * is * gg.w + bb.w);
  *reinterpret_cast<us4*>(hn + (size_t)d * 256 + lane * 4) = out;
}

extern "C" void kernel_launch(void* const* d_in, const int* in_sizes, int n_in,
                              void* d_out, int out_size, void* d_ws, size_t ws_size,
                              hipStream_t stream) {
  const float* X   = (const float*)d_in[0];
  const int*   EI  = (const int*)d_in[1];
  const float* Wi  = (const float*)d_in[2];
  const float* bi  = (const float*)d_in[3];
  const float* wp  = (const float*)d_in[4];
  const float* Wa  = (const float*)d_in[5];
  const float* ba  = (const float*)d_in[6];
  const float* l1g = (const float*)d_in[7];
  const float* l1b = (const float*)d_in[8];
  const float* l2g = (const float*)d_in[9];
  const float* l2b = (const float*)d_in[10];
  const float* W1  = (const float*)d_in[11];
  const float* b1  = (const float*)d_in[12];
  const float* W2  = (const float*)d_in[13];
  const float* b2  = (const float*)d_in[14];
  const float* Wc  = (const float*)d_in[15];
  const float* bc  = (const float*)d_in[16];
  const float* Wo  = (const float*)d_in[17];
  const float* bo  = (const float*)d_in[18];

  const int N = in_sizes[0] / 256;
  const int E = in_sizes[1] / 2;
  const int Et = E + N;
  const int* srcp = EI;
  const int* dstp = EI + E;

  float* ws = (float*)d_ws;
  size_t off = 0;
  auto alloc = [&](size_t n) { float* p = ws + off; off += n; return p; };
  const size_t NH = (size_t)N * 256;
  float*  h    = alloc(NH);                            // f32 [N][256]
  ushort* hn   = (ushort*)alloc(NH / 2);               // bf16 [N][256]
  ushort* xp   = (ushort*)alloc(NH / 2);               // bf16 [N][256]
  ushort* hb   = (ushort*)alloc(NH / 2);               // bf16 [N][256]
  ushort* u    = (ushort*)alloc((size_t)N * 512 / 2);  // bf16 [N][512]
  ushort* WcT  = (ushort*)alloc(3 * 65536 / 2);
  ushort* W1T  = (ushort*)alloc(3 * 131072 / 2);
  ushort* W2T  = (ushort*)alloc(3 * 131072 / 2);
  ushort* WoT  = (ushort*)alloc(16384 / 2);
  float* delta = alloc(N);
  float* adst  = alloc(N);
  float* asrc  = alloc(N);
  float* xwp   = alloc(N);
  float* pib   = alloc(N);
  float* expe  = alloc(Et);
  float* neigh = alloc(N);       // ┐ contiguous zero region (3N)
  float* denom = alloc(N);       // │
  int*   cnt   = (int*)alloc(N); // ┘
  int*   slots = (int*)alloc((size_t)N * 64);
  int*   kcnt  = (int*)alloc(N);
  int*   ksrc  = (int*)alloc((size_t)N * 8);
  float* kw    = alloc((size_t)N * 8);

  // weight transpose+convert
  wtrans_k<<<(3 * 65536 + 255) / 256, 256, 0, stream>>>(Wc, WcT, 256, 256, 3 * 65536);
  wtrans_k<<<(3 * 131072 + 255) / 256, 256, 0, stream>>>(W1, W1T, 256, 512, 3 * 131072);
  wtrans_k<<<(3 * 131072 + 255) / 256, 256, 0, stream>>>(W2, W2T, 512, 256, 3 * 131072);
  wtrans_k<<<(16384 + 255) / 256, 256, 0, stream>>>(Wo, WoT, 256, 64, 16384);

  // zero atomic accumulators
  zero_k<<<(3 * N + 255) / 256, 256, 0, stream>>>(neigh, 3 * N);

  // input projection + relu + fused row stats (f32: exact top-k path)
  gemm_in<<<(N + 63) / 64, 256, 0, stream>>>(X, Wi, bi, Wa, wp, h,
                                             delta, adst, asrc, xwp, N, 256);
  neigh_k<<<(E + 255) / 256, 256, 0, stream>>>(srcp, dstp, delta, neigh, E);
  pi_k<<<(N + 255) / 256, 256, 0, stream>>>(xwp, neigh, pib, N);
  logits_k<<<(Et + 255) / 256, 256, 0, stream>>>(srcp, dstp, adst, asrc, pib, Wa, ba,
                                                 expe, denom, cnt, slots, E, Et, N);
  topk_k<<<(N + 255) / 256, 256, 0, stream>>>(cnt, slots, expe, denom, srcp,
                                              kcnt, ksrc, kw, N, E);

  const int GM = (N + 127) / 128;
  for (int l = 0; l < 3; ++l) {
    ln_k<<<(N + 3) / 4, 256, 0, stream>>>(h, l1g + l * 256, l1b + l * 256, hn, N);
    gemm_mfma<1><<<dim3(GM, 2), 256, 0, stream>>>(
        hn, WcT + (size_t)l * 65536, bc + l * 256, nullptr, xp, N, 256, 256);
    agg_ln_k<<<(N + 3) / 4, 256, 0, stream>>>(xp, kcnt, ksrc, kw,
                                              l2g + l * 256, l2b + l * 256, h, hn, N);
    gemm_mfma<2><<<dim3(GM, 4), 256, 0, stream>>>(
        hn, W1T + (size_t)l * 131072, b1 + l * 512, nullptr, u, N, 512, 256);
    if (l < 2)
      gemm_mfma<3><<<dim3(GM, 2), 256, 0, stream>>>(
          u, W2T + (size_t)l * 131072, b2 + l * 256, h, nullptr, N, 256, 512);
    else
      gemm_mfma<4><<<dim3(GM, 2), 256, 0, stream>>>(
          u, W2T + (size_t)l * 131072, b2 + l * 256, h, hb, N, 256, 512);
  }
  // output projection (bf16 MFMA)
  gemm_out<<<(N + 127) / 128, 256, 0, stream>>>(hb, WoT, bo, (float*)d_out, N);
}